// Round 5
// baseline (273.350 us; speedup 1.0000x reference)
//
#include <hip/hip_runtime.h>
#include <math.h>

#define N_ 128
#define I_ 256
#define O_ 256
#define P_ 16
#define OT 4      // o's per block
#define IT 8      // i's per block
#define ICH 4     // i's set up per phase-A pass
#define LSTR 20   // padded column stride for LinvT (16B-aligned, 2-way banks)
#define SQRT_2PI 2.5066282746310002f
#define INV_SQRT_2PI 0.3989422804014327f

typedef float f2 __attribute__((ext_vector_type(2)));

// grid: 64 o-tiles * 32 i-ranges = 2048 blocks, 256 threads.
// Phase A: 4i x 4o = 16 groups x 16 lanes, in-register Cholesky+inv (2 passes).
// Phase B: each thread owns (o, 2 sites) packed into float2 lanes -> all hot
// math is v_pk_fma_f32 (2 FMA/inst, the only path to the 157 TF fp32 peak).
// Wave = one o-group => LinvT b128 reads are pure broadcast.
// R2 lesson: never force min-waves=4 (VGPR cap 64 -> 600MB spill).
// R3 lesson: scalar ds_read per FMA -> LDS-pipe-bound.
// R4 lesson: scalar fp32 phase B is VALU-issue-bound at ~960 inst/(wave,i).
__global__ __launch_bounds__(256, 2) void gp_fused(
    const float* __restrict__ x_mean, const float* __restrict__ x_var,
    const float* __restrict__ z_param, const float* __restrict__ h,
    const float* __restrict__ l_param, const float* __restrict__ s_param,
    const float* __restrict__ jitter_param, float* __restrict__ out)
{
    __shared__ float xm_s[N_][IT + 1];
    __shared__ float xv_s[N_][IT + 1];
    __shared__ __align__(16) float LinvT[ICH][OT][P_][LSTR]; // [i][o][col][row+pad]
    __shared__ __align__(16) float zS[ICH][OT][P_];
    __shared__ __align__(16) float wS[ICH][OT][P_];
    __shared__ float scS[ICH][OT][2];            // l2, s^2*l

    const int t = threadIdx.x;
    const int b = blockIdx.x;
    const int ot = b & 63;         // 64 o-tiles
    const int ir = b >> 6;         // 32 i-ranges
    const int o_base = ot * OT;
    const int i0 = ir * IT;

    // ---- stage x slice (coalesced float4 loads, once per block) ----
    {
        const int n = t >> 1, q = t & 1;
        const float4 xm4 = *(const float4*)(x_mean + n * I_ + i0 + q * 4);
        const float4 xv4 = *(const float4*)(x_var  + n * I_ + i0 + q * 4);
        xm_s[n][q*4+0] = xm4.x; xm_s[n][q*4+1] = xm4.y;
        xm_s[n][q*4+2] = xm4.z; xm_s[n][q*4+3] = xm4.w;
        xv_s[n][q*4+0] = xv4.x; xv_s[n][q*4+1] = xv4.y;
        xv_s[n][q*4+2] = xv4.z; xv_s[n][q*4+3] = xv4.w;
    }
    __syncthreads();

    f2 am2 = {0.f, 0.f};
    f2 av2 = {IT * 0.1f, IT * 0.1f};   // GLOBAL_JITTER per i

    const int ol = t >> 6;   // phase B: o_local (0..3), one per wave
    const int ln = t & 63;   // site lane; sites n = ln and ln+64
    const int g2 = t >> 4;   // phase A: group 0..15
    const int il = g2 >> 2;  // which i of the 4-chunk
    const int g  = g2 & 3;   // o group
    const int p  = t & 15;   // lane-in-group

    for (int ii4 = 0; ii4 < IT / ICH; ++ii4) {

        // ======== Phase A: per-pair setup for 4 i's (all 256 threads) =======
        {
            const int i  = i0 + ii4 * ICH + il;
            const int o  = o_base + g;
            const int io = i * O_ + o;
            const float l   = expf(l_param[io]) + 0.2f;
            const float s   = expf(s_param[io]) + 0.1f;
            const float jit = expf(jitter_param[io]) + 0.01f;
            const float l2 = l * l;
            const float inv2l2 = 0.5f / l2;
            const float cQ = INV_SQRT_2PI / l;
            const float noise = jit * jit / (s * s * l * SQRT_2PI);

            const float zp = tanhf(z_param[io * P_ + p]);

            // build row p of Q (row-per-lane)
            float a[P_];
            #pragma unroll
            for (int c = 0; c < P_; ++c) {
                const float zc = __shfl(zp, c, P_);
                const float d = zp - zc;
                a[c] = cQ * __expf(-d * d * inv2l2) + ((c == p) ? noise : 0.0f);
            }

            // in-register Cholesky (row-per-lane, static indices only)
            #pragma unroll
            for (int k = 0; k < P_; ++k) {
                const float akk = __shfl(a[k], k, P_);
                const float lkk = sqrtf(akk);
                const float inv_lkk = 1.0f / lkk;
                if (p == k)      a[k] = lkk;
                else if (p > k)  a[k] *= inv_lkk;
                const float lrk = a[k];   // own L[p][k] (valid for p>=k)
                #pragma unroll
                for (int c = k + 1; c < P_; ++c) {
                    const float lck = __shfl(a[k], c, P_);  // L[c][k]
                    if (p >= c) a[c] -= lrk * lck;
                }
            }

            // M = L^-1, column-per-lane (lane p computes column p)
            float x[P_];
            #pragma unroll
            for (int r = 0; r < P_; ++r) {
                const float lrr = __shfl(a[r], r, P_);
                float acc = (r == p) ? 1.0f : 0.0f;
                #pragma unroll
                for (int m = 0; m < r; ++m) {
                    const float lrm = __shfl(a[m], r, P_);  // L[r][m]
                    acc -= lrm * x[m];
                }
                x[r] = acc / lrr;   // exactly 0 for r < p
            }

            // w = M^T (M h)
            const float hc = h[io * P_ + p];
            float y[P_];
            #pragma unroll
            for (int r = 0; r < P_; ++r) y[r] = x[r] * hc;
            #pragma unroll
            for (int off = 8; off >= 1; off >>= 1) {
                #pragma unroll
                for (int r = 0; r < P_; ++r) y[r] += __shfl_xor(y[r], off, P_);
            }
            float wc = 0.f;
            #pragma unroll
            for (int r = 0; r < P_; ++r) wc += x[r] * y[r];

            // publish: lane p writes COLUMN p contiguously (4x b128, 2-way banks)
            float4* dst = (float4*)&LinvT[il][g][p][0];
            dst[0] = make_float4(x[ 0], x[ 1], x[ 2], x[ 3]);
            dst[1] = make_float4(x[ 4], x[ 5], x[ 6], x[ 7]);
            dst[2] = make_float4(x[ 8], x[ 9], x[10], x[11]);
            dst[3] = make_float4(x[12], x[13], x[14], x[15]);
            zS[il][g][p] = zp;
            wS[il][g][p] = wc;
            if (p == 0) { scS[il][g][0] = l2; scS[il][g][1] = s * s * l; }
        }
        __syncthreads();

        // ======== Phase B: packed per-site work, 4 i's ========
        #pragma unroll
        for (int il2 = 0; il2 < ICH; ++il2) {
            const int iiA = ii4 * ICH + il2;
            const float l2  = scS[il2][ol][0];
            const float s2l = scS[il2][ol][1];
            const float t4v = SQRT_2PI * s2l;

            float zr[P_], wr[P_];
            {
                const float4* zp4 = (const float4*)&zS[il2][ol][0];
                const float4* wp4 = (const float4*)&wS[il2][ol][0];
                #pragma unroll
                for (int c = 0; c < 4; ++c) {
                    const float4 z4 = zp4[c], w4 = wp4[c];
                    zr[4*c+0] = z4.x; zr[4*c+1] = z4.y; zr[4*c+2] = z4.z; zr[4*c+3] = z4.w;
                    wr[4*c+0] = w4.x; wr[4*c+1] = w4.y; wr[4*c+2] = w4.z; wr[4*c+3] = w4.w;
                }
            }

            f2 xm2, xv2;
            xm2.x = xm_s[ln][iiA];       xm2.y = xm_s[ln + 64][iiA];
            xv2.x = xv_s[ln][iiA];       xv2.y = xv_s[ln + 64][iiA];
            f2 v2 = xv2 + l2;
            f2 cc2, nh2;
            cc2.x = rsqrtf(v2.x) * INV_SQRT_2PI;
            cc2.y = rsqrtf(v2.y) * INV_SQRT_2PI;
            nh2.x = -0.5f / v2.x;
            nh2.y = -0.5f / v2.y;
            f2 dm2 = {0.f, 0.f};

            f2 u2[P_];   // u2[r] = (L^-1 e)[r] for both packed sites
            #pragma unroll
            for (int m = 0; m < P_; ++m) {
                f2 d2 = xm2 - zr[m];
                f2 tt = d2 * d2 * nh2;
                f2 em2;
                em2.x = __expf(tt.x);
                em2.y = __expf(tt.y);
                dm2 += em2 * wr[m];
                const int c0 = m >> 2;   // static after unroll
                #pragma unroll
                for (int c = 0; c < 4; ++c) {
                    if (c < c0) continue;  // aligned chunks above diag: skip
                    const float4 L4 = *(const float4*)&LinvT[il2][ol][m][4*c];
                    if (m == 0) {
                        u2[4*c+0] = L4.x * em2;
                        u2[4*c+1] = L4.y * em2;
                        u2[4*c+2] = L4.z * em2;
                        u2[4*c+3] = L4.w * em2;
                    } else {
                        u2[4*c+0] += L4.x * em2;
                        u2[4*c+1] += L4.y * em2;
                        u2[4*c+2] += L4.z * em2;
                        u2[4*c+3] += L4.w * em2;
                    }
                }
            }

            f2 su2 = {0.f, 0.f};
            #pragma unroll
            for (int r = 0; r < P_; ++r) su2 += u2[r] * u2[r];

            am2 += cc2 * dm2;
            f2 t32;
            t32.x = s2l * rsqrtf(l2 + 2.f * xv2.x);
            t32.y = s2l * rsqrtf(l2 + 2.f * xv2.y);
            av2 += t32 - t4v * (cc2 * cc2) * su2;
        }
        __syncthreads();
    }

    // ---- accumulate into output (32 i-range blocks contend per address) ----
    const int o = o_base + ol;
    atomicAdd(out + ln * O_ + o,               am2.x);
    atomicAdd(out + (ln + 64) * O_ + o,        am2.y);
    atomicAdd(out + N_ * O_ + ln * O_ + o,        av2.x);
    atomicAdd(out + N_ * O_ + (ln + 64) * O_ + o, av2.y);
}

extern "C" void kernel_launch(void* const* d_in, const int* in_sizes, int n_in,
                              void* d_out, int out_size, void* d_ws, size_t ws_size,
                              hipStream_t stream) {
    const float* x_mean = (const float*)d_in[0];
    const float* x_var  = (const float*)d_in[1];
    const float* z_param = (const float*)d_in[2];
    const float* h       = (const float*)d_in[3];
    const float* l_param = (const float*)d_in[4];
    const float* s_param = (const float*)d_in[5];
    const float* jitter_param = (const float*)d_in[6];
    float* out = (float*)d_out;

    hipMemsetAsync(d_out, 0, (size_t)out_size * sizeof(float), stream);
    gp_fused<<<dim3(2048), dim3(256), 0, stream>>>(
        x_mean, x_var, z_param, h, l_param, s_param, jitter_param, out);
}

// Round 6
// 249.970 us; speedup vs baseline: 1.0935x; 1.0935x over previous
//
#include <hip/hip_runtime.h>
#include <math.h>

#define N_ 128
#define I_ 256
#define O_ 256
#define P_ 16
#define OT 4      // o's per block (site kernel)
#define IT 8      // i's per block (site kernel)
#define ICH 4     // i's staged per chunk
#define PSTR 292  // floats per pair record: 256 Linv + 16 z + 16 w + 2 sc + 2 pad
#define SQRT_2PI 2.5066282746310002f
#define INV_SQRT_2PI 0.3989422804014327f

typedef float f2 __attribute__((ext_vector_type(2)));

// ============================ Kernel 1: pairs ==============================
// One 16-lane group per (i,o) pair: build Q, Cholesky, M=L^-1, w=Q^-1 h.
// 65536 pairs -> 4096 blocks x 16 groups. No barriers, no LDS: latency of the
// shfl chains is hidden by ~20 resident waves/SIMD worth of independent pairs.
// Record layout at ws + q*PSTR (q = ot*1024 + i*4 + g):
//   [p*16 + r]  = M[r][p]  (column-major L^-1)
//   [256 + p]   = z_p,  [272 + p] = w_p,  [288] = l^2, [289] = s^2*l
__global__ __launch_bounds__(256, 2) void gp_pairs(
    const float* __restrict__ z_param, const float* __restrict__ h,
    const float* __restrict__ l_param, const float* __restrict__ s_param,
    const float* __restrict__ jitter_param, float* __restrict__ ws)
{
    const int t = threadIdx.x;
    const int q = blockIdx.x * 16 + (t >> 4);   // pair index
    const int p = t & 15;
    const int ot   = q >> 10;
    const int rest = q & 1023;
    const int i = rest >> 2;
    const int g = rest & 3;
    const int o = ot * 4 + g;
    const int io = i * O_ + o;

    const float l   = expf(l_param[io]) + 0.2f;
    const float s   = expf(s_param[io]) + 0.1f;
    const float jit = expf(jitter_param[io]) + 0.01f;
    const float l2 = l * l;
    const float inv2l2 = 0.5f / l2;
    const float cQ = INV_SQRT_2PI / l;
    const float noise = jit * jit / (s * s * l * SQRT_2PI);

    const float zp = tanhf(z_param[io * P_ + p]);

    // row p of Q
    float a[P_];
    #pragma unroll
    for (int c = 0; c < P_; ++c) {
        const float zc = __shfl(zp, c, P_);
        const float d = zp - zc;
        a[c] = cQ * __expf(-d * d * inv2l2) + ((c == p) ? noise : 0.0f);
    }

    // in-register Cholesky (row-per-lane)
    #pragma unroll
    for (int k = 0; k < P_; ++k) {
        const float akk = __shfl(a[k], k, P_);
        const float lkk = sqrtf(akk);
        const float inv_lkk = 1.0f / lkk;
        if (p == k)      a[k] = lkk;
        else if (p > k)  a[k] *= inv_lkk;
        const float lrk = a[k];
        #pragma unroll
        for (int c = k + 1; c < P_; ++c) {
            const float lck = __shfl(a[k], c, P_);
            if (p >= c) a[c] -= lrk * lck;
        }
    }

    // M = L^-1, column-per-lane (lane p = column p)
    float x[P_];
    #pragma unroll
    for (int r = 0; r < P_; ++r) {
        const float lrr = __shfl(a[r], r, P_);
        float acc = (r == p) ? 1.0f : 0.0f;
        #pragma unroll
        for (int m = 0; m < r; ++m) {
            const float lrm = __shfl(a[m], r, P_);
            acc -= lrm * x[m];
        }
        x[r] = acc / lrr;
    }

    // w = Q^-1 h: forward solve L tr = h (row-per-lane), then w_c = dot(x, t)
    float tr = h[io * P_ + p];
    #pragma unroll
    for (int m = 0; m < P_; ++m) {
        if (p == m) tr = tr / a[m];        // a[m] on lane m is L[m][m]
        const float tm = __shfl(tr, m, P_);
        if (p > m) tr -= a[m] * tm;        // a[m] = L[p][m] for p>m
    }
    float wc = 0.f;
    #pragma unroll
    for (int r = 0; r < P_; ++r) {
        const float tb = __shfl(tr, r, P_);
        wc += x[r] * tb;
    }

    // write record
    float* dst = ws + (size_t)q * PSTR;
    float4* dc = (float4*)(dst + p * 16);
    dc[0] = make_float4(x[ 0], x[ 1], x[ 2], x[ 3]);
    dc[1] = make_float4(x[ 4], x[ 5], x[ 6], x[ 7]);
    dc[2] = make_float4(x[ 8], x[ 9], x[10], x[11]);
    dc[3] = make_float4(x[12], x[13], x[14], x[15]);
    dst[256 + p] = zp;
    dst[272 + p] = wc;
    if (p == 0) { dst[288] = l2; dst[289] = s * s * l; }
}

// ============================ Kernel 2: sites ==============================
// grid: 64 o-tiles * 32 i-ranges = 2048 blocks. Per chunk of 4 i's: stage
// 16 pair records (18.7 KB) via coalesced float4 copy, then packed phase B
// (f2 lanes = 2 sites/thread, v_pk_fma_f32). Wave = one o -> LDS broadcast.
__global__ __launch_bounds__(256, 2) void gp_sites(
    const float* __restrict__ x_mean, const float* __restrict__ x_var,
    const float* __restrict__ ws, float* __restrict__ out)
{
    __shared__ float xm_s[N_][IT + 1];
    __shared__ float xv_s[N_][IT + 1];
    __shared__ __align__(16) float pb[16][PSTR];   // 16 pair records

    const int t = threadIdx.x;
    const int b = blockIdx.x;
    const int ot = b & 63;
    const int ir = b >> 6;
    const int o_base = ot * OT;
    const int i0 = ir * IT;

    {
        const int n = t >> 1, qq = t & 1;
        const float4 xm4 = *(const float4*)(x_mean + n * I_ + i0 + qq * 4);
        const float4 xv4 = *(const float4*)(x_var  + n * I_ + i0 + qq * 4);
        xm_s[n][qq*4+0] = xm4.x; xm_s[n][qq*4+1] = xm4.y;
        xm_s[n][qq*4+2] = xm4.z; xm_s[n][qq*4+3] = xm4.w;
        xv_s[n][qq*4+0] = xv4.x; xv_s[n][qq*4+1] = xv4.y;
        xv_s[n][qq*4+2] = xv4.z; xv_s[n][qq*4+3] = xv4.w;
    }

    f2 am2 = {0.f, 0.f};
    f2 av2 = {IT * 0.1f, IT * 0.1f};   // GLOBAL_JITTER per i

    const int ol = t >> 6;   // o_local (0..3), one per wave
    const int ln = t & 63;   // sites n = ln and ln+64

    for (int ii4 = 0; ii4 < IT / ICH; ++ii4) {
        __syncthreads();
        // stage 16 pair records: pairs q = ot*1024 + (i0+ii4*4)*4 .. +16
        {
            const float4* src = (const float4*)(ws +
                ((size_t)ot * 1024 + (size_t)(i0 + ii4 * ICH) * 4) * PSTR);
            float4* dstl = (float4*)&pb[0][0];
            #pragma unroll
            for (int k = 0; k < 5; ++k) {
                const int idx = t + k * 256;
                if (idx < 16 * PSTR / 4) dstl[idx] = src[idx];
            }
        }
        __syncthreads();

        #pragma unroll
        for (int il2 = 0; il2 < ICH; ++il2) {
            const int iiA = ii4 * ICH + il2;
            const float* pr = &pb[il2 * 4 + ol][0];
            const float l2  = pr[288];
            const float s2l = pr[289];
            const float t4v = SQRT_2PI * s2l;

            float zr[P_], wr[P_];
            {
                const float4* zp4 = (const float4*)(pr + 256);
                const float4* wp4 = (const float4*)(pr + 272);
                #pragma unroll
                for (int c = 0; c < 4; ++c) {
                    const float4 z4 = zp4[c], w4 = wp4[c];
                    zr[4*c+0] = z4.x; zr[4*c+1] = z4.y; zr[4*c+2] = z4.z; zr[4*c+3] = z4.w;
                    wr[4*c+0] = w4.x; wr[4*c+1] = w4.y; wr[4*c+2] = w4.z; wr[4*c+3] = w4.w;
                }
            }

            f2 xm2, xv2;
            xm2.x = xm_s[ln][iiA];       xm2.y = xm_s[ln + 64][iiA];
            xv2.x = xv_s[ln][iiA];       xv2.y = xv_s[ln + 64][iiA];
            f2 v2 = xv2 + l2;
            f2 cc2, nh2;
            cc2.x = rsqrtf(v2.x) * INV_SQRT_2PI;
            cc2.y = rsqrtf(v2.y) * INV_SQRT_2PI;
            nh2.x = -0.5f / v2.x;
            nh2.y = -0.5f / v2.y;
            f2 dm2 = {0.f, 0.f};

            f2 u2[P_];
            #pragma unroll
            for (int m = 0; m < P_; ++m) {
                f2 d2 = xm2 - zr[m];
                f2 tt = d2 * d2 * nh2;
                f2 em2;
                em2.x = __expf(tt.x);
                em2.y = __expf(tt.y);
                dm2 += em2 * wr[m];
                const int c0 = m >> 2;
                #pragma unroll
                for (int c = 0; c < 4; ++c) {
                    if (c < c0) continue;   // M[r][m]=0 for r<m (chunked)
                    const float4 L4 = *(const float4*)(pr + m * 16 + 4 * c);
                    if (m == 0) {
                        u2[4*c+0] = L4.x * em2;
                        u2[4*c+1] = L4.y * em2;
                        u2[4*c+2] = L4.z * em2;
                        u2[4*c+3] = L4.w * em2;
                    } else {
                        u2[4*c+0] += L4.x * em2;
                        u2[4*c+1] += L4.y * em2;
                        u2[4*c+2] += L4.z * em2;
                        u2[4*c+3] += L4.w * em2;
                    }
                }
            }

            f2 su2 = {0.f, 0.f};
            #pragma unroll
            for (int r = 0; r < P_; ++r) su2 += u2[r] * u2[r];

            am2 += cc2 * dm2;
            f2 t32;
            t32.x = s2l * rsqrtf(l2 + 2.f * xv2.x);
            t32.y = s2l * rsqrtf(l2 + 2.f * xv2.y);
            av2 += t32 - t4v * (cc2 * cc2) * su2;
        }
    }

    const int o = o_base + ol;
    atomicAdd(out + ln * O_ + o,                  am2.x);
    atomicAdd(out + (ln + 64) * O_ + o,           am2.y);
    atomicAdd(out + N_ * O_ + ln * O_ + o,        av2.x);
    atomicAdd(out + N_ * O_ + (ln + 64) * O_ + o, av2.y);
}

// ===================== Fallback: R5 monolithic kernel ======================
#define LSTR 20
__global__ __launch_bounds__(256, 2) void gp_fused(
    const float* __restrict__ x_mean, const float* __restrict__ x_var,
    const float* __restrict__ z_param, const float* __restrict__ h,
    const float* __restrict__ l_param, const float* __restrict__ s_param,
    const float* __restrict__ jitter_param, float* __restrict__ out)
{
    __shared__ float xm_s[N_][IT + 1];
    __shared__ float xv_s[N_][IT + 1];
    __shared__ __align__(16) float LinvT[ICH][OT][P_][LSTR];
    __shared__ __align__(16) float zS[ICH][OT][P_];
    __shared__ __align__(16) float wS[ICH][OT][P_];
    __shared__ float scS[ICH][OT][2];

    const int t = threadIdx.x;
    const int b = blockIdx.x;
    const int ot = b & 63;
    const int ir = b >> 6;
    const int o_base = ot * OT;
    const int i0 = ir * IT;

    {
        const int n = t >> 1, q = t & 1;
        const float4 xm4 = *(const float4*)(x_mean + n * I_ + i0 + q * 4);
        const float4 xv4 = *(const float4*)(x_var  + n * I_ + i0 + q * 4);
        xm_s[n][q*4+0] = xm4.x; xm_s[n][q*4+1] = xm4.y;
        xm_s[n][q*4+2] = xm4.z; xm_s[n][q*4+3] = xm4.w;
        xv_s[n][q*4+0] = xv4.x; xv_s[n][q*4+1] = xv4.y;
        xv_s[n][q*4+2] = xv4.z; xv_s[n][q*4+3] = xv4.w;
    }
    __syncthreads();

    f2 am2 = {0.f, 0.f};
    f2 av2 = {IT * 0.1f, IT * 0.1f};

    const int ol = t >> 6;
    const int ln = t & 63;
    const int g2 = t >> 4;
    const int il = g2 >> 2;
    const int g  = g2 & 3;
    const int p  = t & 15;

    for (int ii4 = 0; ii4 < IT / ICH; ++ii4) {
        {
            const int i  = i0 + ii4 * ICH + il;
            const int o  = o_base + g;
            const int io = i * O_ + o;
            const float l   = expf(l_param[io]) + 0.2f;
            const float s   = expf(s_param[io]) + 0.1f;
            const float jit = expf(jitter_param[io]) + 0.01f;
            const float l2 = l * l;
            const float inv2l2 = 0.5f / l2;
            const float cQ = INV_SQRT_2PI / l;
            const float noise = jit * jit / (s * s * l * SQRT_2PI);
            const float zp = tanhf(z_param[io * P_ + p]);

            float a[P_];
            #pragma unroll
            for (int c = 0; c < P_; ++c) {
                const float zc = __shfl(zp, c, P_);
                const float d = zp - zc;
                a[c] = cQ * __expf(-d * d * inv2l2) + ((c == p) ? noise : 0.0f);
            }
            #pragma unroll
            for (int k = 0; k < P_; ++k) {
                const float akk = __shfl(a[k], k, P_);
                const float lkk = sqrtf(akk);
                const float inv_lkk = 1.0f / lkk;
                if (p == k)      a[k] = lkk;
                else if (p > k)  a[k] *= inv_lkk;
                const float lrk = a[k];
                #pragma unroll
                for (int c = k + 1; c < P_; ++c) {
                    const float lck = __shfl(a[k], c, P_);
                    if (p >= c) a[c] -= lrk * lck;
                }
            }
            float x[P_];
            #pragma unroll
            for (int r = 0; r < P_; ++r) {
                const float lrr = __shfl(a[r], r, P_);
                float acc = (r == p) ? 1.0f : 0.0f;
                #pragma unroll
                for (int m = 0; m < r; ++m) {
                    const float lrm = __shfl(a[m], r, P_);
                    acc -= lrm * x[m];
                }
                x[r] = acc / lrr;
            }
            const float hc = h[io * P_ + p];
            float y[P_];
            #pragma unroll
            for (int r = 0; r < P_; ++r) y[r] = x[r] * hc;
            #pragma unroll
            for (int off = 8; off >= 1; off >>= 1) {
                #pragma unroll
                for (int r = 0; r < P_; ++r) y[r] += __shfl_xor(y[r], off, P_);
            }
            float wc = 0.f;
            #pragma unroll
            for (int r = 0; r < P_; ++r) wc += x[r] * y[r];

            float4* dst = (float4*)&LinvT[il][g][p][0];
            dst[0] = make_float4(x[ 0], x[ 1], x[ 2], x[ 3]);
            dst[1] = make_float4(x[ 4], x[ 5], x[ 6], x[ 7]);
            dst[2] = make_float4(x[ 8], x[ 9], x[10], x[11]);
            dst[3] = make_float4(x[12], x[13], x[14], x[15]);
            zS[il][g][p] = zp;
            wS[il][g][p] = wc;
            if (p == 0) { scS[il][g][0] = l2; scS[il][g][1] = s * s * l; }
        }
        __syncthreads();

        #pragma unroll
        for (int il2 = 0; il2 < ICH; ++il2) {
            const int iiA = ii4 * ICH + il2;
            const float l2  = scS[il2][ol][0];
            const float s2l = scS[il2][ol][1];
            const float t4v = SQRT_2PI * s2l;
            float zr[P_], wr[P_];
            {
                const float4* zp4 = (const float4*)&zS[il2][ol][0];
                const float4* wp4 = (const float4*)&wS[il2][ol][0];
                #pragma unroll
                for (int c = 0; c < 4; ++c) {
                    const float4 z4 = zp4[c], w4 = wp4[c];
                    zr[4*c+0] = z4.x; zr[4*c+1] = z4.y; zr[4*c+2] = z4.z; zr[4*c+3] = z4.w;
                    wr[4*c+0] = w4.x; wr[4*c+1] = w4.y; wr[4*c+2] = w4.z; wr[4*c+3] = w4.w;
                }
            }
            f2 xm2, xv2;
            xm2.x = xm_s[ln][iiA];       xm2.y = xm_s[ln + 64][iiA];
            xv2.x = xv_s[ln][iiA];       xv2.y = xv_s[ln + 64][iiA];
            f2 v2 = xv2 + l2;
            f2 cc2, nh2;
            cc2.x = rsqrtf(v2.x) * INV_SQRT_2PI;
            cc2.y = rsqrtf(v2.y) * INV_SQRT_2PI;
            nh2.x = -0.5f / v2.x;
            nh2.y = -0.5f / v2.y;
            f2 dm2 = {0.f, 0.f};
            f2 u2[P_];
            #pragma unroll
            for (int m = 0; m < P_; ++m) {
                f2 d2 = xm2 - zr[m];
                f2 tt = d2 * d2 * nh2;
                f2 em2;
                em2.x = __expf(tt.x);
                em2.y = __expf(tt.y);
                dm2 += em2 * wr[m];
                const int c0 = m >> 2;
                #pragma unroll
                for (int c = 0; c < 4; ++c) {
                    if (c < c0) continue;
                    const float4 L4 = *(const float4*)&LinvT[il2][ol][m][4*c];
                    if (m == 0) {
                        u2[4*c+0] = L4.x * em2;
                        u2[4*c+1] = L4.y * em2;
                        u2[4*c+2] = L4.z * em2;
                        u2[4*c+3] = L4.w * em2;
                    } else {
                        u2[4*c+0] += L4.x * em2;
                        u2[4*c+1] += L4.y * em2;
                        u2[4*c+2] += L4.z * em2;
                        u2[4*c+3] += L4.w * em2;
                    }
                }
            }
            f2 su2 = {0.f, 0.f};
            #pragma unroll
            for (int r = 0; r < P_; ++r) su2 += u2[r] * u2[r];
            am2 += cc2 * dm2;
            f2 t32;
            t32.x = s2l * rsqrtf(l2 + 2.f * xv2.x);
            t32.y = s2l * rsqrtf(l2 + 2.f * xv2.y);
            av2 += t32 - t4v * (cc2 * cc2) * su2;
        }
        __syncthreads();
    }

    const int o = o_base + ol;
    atomicAdd(out + ln * O_ + o,                  am2.x);
    atomicAdd(out + (ln + 64) * O_ + o,           am2.y);
    atomicAdd(out + N_ * O_ + ln * O_ + o,        av2.x);
    atomicAdd(out + N_ * O_ + (ln + 64) * O_ + o, av2.y);
}

extern "C" void kernel_launch(void* const* d_in, const int* in_sizes, int n_in,
                              void* d_out, int out_size, void* d_ws, size_t ws_size,
                              hipStream_t stream) {
    const float* x_mean = (const float*)d_in[0];
    const float* x_var  = (const float*)d_in[1];
    const float* z_param = (const float*)d_in[2];
    const float* h       = (const float*)d_in[3];
    const float* l_param = (const float*)d_in[4];
    const float* s_param = (const float*)d_in[5];
    const float* jitter_param = (const float*)d_in[6];
    float* out = (float*)d_out;

    const size_t need = (size_t)I_ * O_ * PSTR * sizeof(float);  // 76.5 MB
    hipMemsetAsync(d_out, 0, (size_t)out_size * sizeof(float), stream);
    if (ws_size >= need) {
        gp_pairs<<<dim3(4096), dim3(256), 0, stream>>>(
            z_param, h, l_param, s_param, jitter_param, (float*)d_ws);
        gp_sites<<<dim3(2048), dim3(256), 0, stream>>>(
            x_mean, x_var, (const float*)d_ws, out);
    } else {
        gp_fused<<<dim3(2048), dim3(256), 0, stream>>>(
            x_mean, x_var, z_param, h, l_param, s_param, jitter_param, out);
    }
}